// Round 10
// baseline (332.455 us; speedup 1.0000x reference)
//
#include <hip/hip_runtime.h>
#include <hip/hip_bf16.h>

typedef float ff4 __attribute__((ext_vector_type(4)));
typedef short s8v __attribute__((ext_vector_type(8)));
typedef unsigned int u4v __attribute__((ext_vector_type(4)));
typedef unsigned int u2v __attribute__((ext_vector_type(2)));

#define Hd 1024
#define Nn 256
#define RB 16
#define SSTR 1032   // sS/sD row stride in ushorts (1024 + 8 pad)

__device__ __forceinline__ unsigned bf16r(float f) {
    unsigned u = __builtin_bit_cast(unsigned, f);
    return (u + 0x7FFFu + ((u >> 16) & 1u)) >> 16;   // RNE f32->bf16
}

__device__ __forceinline__ unsigned cvtpk(float lo, float hi) {
    unsigned r;
    asm("v_cvt_pk_bf16_f32 %0, %1, %2" : "=v"(r) : "v"(lo), "v"(hi));
    return r;
}

// ---- memB chunk-major LINEAR: memB[c*8192 + r*32 + col] = bf16(mem[r][c*32+col]) ----
__global__ void conv_mem_kernel(const float* __restrict__ mem, unsigned short* __restrict__ memB) {
    int g = blockIdx.x * 256 + threadIdx.x;   // 0..32767
    int b = g & 3;
    int r = (g >> 2) & 255;
    int c = g >> 10;
    const float* src = mem + (size_t)r * Hd + c * 32 + b * 8;
    ff4 a0 = *(const ff4*)src;
    ff4 a1 = *(const ff4*)(src + 4);
    u4v v;
    v[0] = bf16r(a0[0]) | (bf16r(a0[1]) << 16);
    v[1] = bf16r(a0[2]) | (bf16r(a0[3]) << 16);
    v[2] = bf16r(a1[0]) | (bf16r(a1[1]) << 16);
    v[3] = bf16r(a1[2]) | (bf16r(a1[3]) << 16);
    *(u4v*)(memB + (size_t)c * 8192 + (size_t)r * 32 + b * 8) = v;
}

// ---- Wbf[c][h] = bf16(Wout[h][c]), c in {0,1} ----
__global__ void conv_w_kernel(const float* __restrict__ Wout, unsigned short* __restrict__ Wbf) {
    int t = threadIdx.x;
    int c = t >> 7;
    int h0 = (t & 127) * 8;
    u4v v;
#pragma unroll
    for (int j = 0; j < 4; ++j) {
        unsigned lo = bf16r(Wout[(h0 + 2 * j) * 2 + c]);
        unsigned hi = bf16r(Wout[(h0 + 2 * j + 1) * 2 + c]);
        v[j] = lo | (hi << 16);
    }
    *(u4v*)(Wbf + (size_t)c * Hd + h0) = v;
}

// ---- Gram G = mem @ mem^T, chunk-major: Gcm[(gj>>5)*8192 + gi*32 + (gj&31)] ----
__global__ __launch_bounds__(256) void gram_kernel(const float* __restrict__ mem,
                                                   unsigned short* __restrict__ Gcm) {
    __shared__ float LA[32][132];
    __shared__ float LB[32][132];
    const int t = threadIdx.x;
    const int bi = blockIdx.x >> 3, bj = blockIdx.x & 7;
    const int j = t & 31, i0 = t >> 5;
    float acc0 = 0.f, acc1 = 0.f, acc2 = 0.f, acc3 = 0.f;
    for (int kc = 0; kc < Hd; kc += 128) {
        __syncthreads();
#pragma unroll
        for (int q = 0; q < 4; ++q) {
            int c = t + q * 256;
            int r = c >> 5, fc = (c & 31) << 2;
            *(ff4*)&LA[r][fc] = *(const ff4*)(mem + (size_t)(bi * 32 + r) * Hd + kc + fc);
            *(ff4*)&LB[r][fc] = *(const ff4*)(mem + (size_t)(bj * 32 + r) * Hd + kc + fc);
        }
        __syncthreads();
#pragma unroll 4
        for (int kk = 0; kk < 128; kk += 4) {
            ff4 b = *(const ff4*)&LB[j][kk];
            ff4 a0 = *(const ff4*)&LA[i0][kk];
            ff4 a1 = *(const ff4*)&LA[i0 + 8][kk];
            ff4 a2 = *(const ff4*)&LA[i0 + 16][kk];
            ff4 a3 = *(const ff4*)&LA[i0 + 24][kk];
            acc0 += a0[0]*b[0] + a0[1]*b[1] + a0[2]*b[2] + a0[3]*b[3];
            acc1 += a1[0]*b[0] + a1[1]*b[1] + a1[2]*b[2] + a1[3]*b[3];
            acc2 += a2[0]*b[0] + a2[1]*b[1] + a2[2]*b[2] + a2[3]*b[3];
            acc3 += a3[0]*b[0] + a3[1]*b[1] + a3[2]*b[2] + a3[3]*b[3];
        }
    }
    const size_t base = (size_t)bj * 8192 + (size_t)j;
    Gcm[base + (size_t)(bi * 32 + i0 +  0) * 32] = (unsigned short)bf16r(acc0);
    Gcm[base + (size_t)(bi * 32 + i0 +  8) * 32] = (unsigned short)bf16r(acc1);
    Gcm[base + (size_t)(bi * 32 + i0 + 16) * 32] = (unsigned short)bf16r(acc2);
    Gcm[base + (size_t)(bi * 32 + i0 + 24) * 32] = (unsigned short)bf16r(acc3);
}

// ---- fused: 16 rows/block; phase1 = coalesced stream u/m -> sS/sD(LDS bf16);
//      phase2 = GEMM from LDS(A) x L2(B); 4 waves = 4 column-quarters of N=256 ----
__global__ __launch_bounds__(256, 2) void fused_kernel(
    const float* __restrict__ user, const float* __restrict__ music,
    const float* __restrict__ bout, const int* __restrict__ label,
    const unsigned short* __restrict__ memB,   // [32][256][32] bf16 chunk-major
    const unsigned short* __restrict__ Wbf,    // [2][1024] bf16
    const unsigned short* __restrict__ Gcm,    // [8][256][32] bf16 chunk-major
    float* __restrict__ out, float* __restrict__ partials)
{
    __shared__ __align__(16) unsigned short sS[RB * SSTR];   // 33024 B
    __shared__ __align__(16) unsigned short sD[RB * SSTR];   // 33024 B
    __shared__ float fMax[64], fSum[64], fCross[64], fQuad[64], fAux[64];
    unsigned short* sAttn = sS;   // epilogue alias [16][264] (after all sS reads)

    const int t = threadIdx.x;
    const int w = t >> 6;
    const int l = t & 63;
    const int la = l & 15, lb = l >> 4;
    const int row0 = blockIdx.x * RB;

    // ================= PHASE 1: coalesced streaming =================
    {
        const float* uB = user  + (size_t)row0 * Hd + t * 4;
        const float* mB = music + (size_t)row0 * Hd + t * 4;
        float sdp[RB];
#pragma unroll
        for (int r = 0; r < RB; ++r) sdp[r] = 0.f;
#pragma unroll
        for (int r = 0; r < RB; ++r) {
            ff4 uv = *(const ff4*)(uB + (size_t)r * Hd);
            ff4 mv = *(const ff4*)(mB + (size_t)r * Hd);
            float s0 = uv[0]*mv[0], s1 = uv[1]*mv[1], s2 = uv[2]*mv[2], s3 = uv[3]*mv[3];
            float d0 = uv[0]-mv[0], d1 = uv[1]-mv[1], d2 = uv[2]-mv[2], d3 = uv[3]-mv[3];
            sdp[r] = fmaf(d0,d0,sdp[r]); sdp[r] = fmaf(d1,d1,sdp[r]);
            sdp[r] = fmaf(d2,d2,sdp[r]); sdp[r] = fmaf(d3,d3,sdp[r]);
            u2v vs, vd;
            vs[0] = cvtpk(s0, s1); vs[1] = cvtpk(s2, s3);
            vd[0] = cvtpk(d0, d1); vd[1] = cvtpk(d2, d3);
            *(u2v*)(sS + r * SSTR + t * 4) = vs;
            *(u2v*)(sD + r * SSTR + t * 4) = vd;
        }
        // per-row ||d||^2: reduce across the 256 threads (wave partials -> LDS)
#pragma unroll
        for (int r = 0; r < RB; ++r) {
            float v = sdp[r];
#pragma unroll
            for (int s = 1; s < 64; s <<= 1) v += __shfl_xor(v, s);
            if (l == 0) fAux[w * 16 + r] = v;
        }
    }
    __syncthreads();   // sS/sD + fAux ready

    // ================= PHASE 2: GEMM (A from LDS, B from L2) =================
    const unsigned short* mbase = memB + w * 2048 + la * 32 + lb * 8;   // + k*8192 + nt*512
    const unsigned short* wrowB = Wbf + (size_t)(la < 2 ? la : 1) * Hd + lb * 8;
    const unsigned short* gbase = Gcm + w * 2048 + la * 32 + lb * 8;
    const int aoff = la * SSTR + lb * 8;

    ff4 accL[4], accD[4];
#pragma unroll
    for (int i = 0; i < 4; ++i) { accL[i] = (ff4)0.0f; accD[i] = (ff4)0.0f; }
    ff4 accH = (ff4)0.0f;

    s8v bMa[4], bMb[4], bWa, bWb, aSa, aSb, aDa, aDb;
#pragma unroll
    for (int nt = 0; nt < 4; ++nt) bMa[nt] = *(const s8v*)(mbase + nt * 512);
    bWa = *(const s8v*)(wrowB);
    aSa = *(const s8v*)(sS + aoff);
    aDa = *(const s8v*)(sD + aoff);

    for (int k = 0; k < 32; k += 2) {
        {   // chunk k (parity A); prefetch k+1 -> parity B
            const int kn = (k + 1) & 31;
#pragma unroll
            for (int nt = 0; nt < 4; ++nt)
                bMb[nt] = *(const s8v*)(mbase + (size_t)kn * 8192 + nt * 512);
            bWb = *(const s8v*)(wrowB + kn * 32);
            aSb = *(const s8v*)(sS + aoff + kn * 32);
            aDb = *(const s8v*)(sD + aoff + kn * 32);
#pragma unroll
            for (int nt = 0; nt < 4; ++nt) {
                accL[nt] = __builtin_amdgcn_mfma_f32_16x16x32_bf16(aSa, bMa[nt], accL[nt], 0, 0, 0);
                accD[nt] = __builtin_amdgcn_mfma_f32_16x16x32_bf16(aDa, bMa[nt], accD[nt], 0, 0, 0);
            }
            accH = __builtin_amdgcn_mfma_f32_16x16x32_bf16(aSa, bWa, accH, 0, 0, 0);
        }
        {   // chunk k+1 (parity B); prefetch k+2 -> parity A
            const int kn = (k + 2) & 31;
#pragma unroll
            for (int nt = 0; nt < 4; ++nt)
                bMa[nt] = *(const s8v*)(mbase + (size_t)kn * 8192 + nt * 512);
            bWa = *(const s8v*)(wrowB + kn * 32);
            aSa = *(const s8v*)(sS + aoff + kn * 32);
            aDa = *(const s8v*)(sD + aoff + kn * 32);
#pragma unroll
            for (int nt = 0; nt < 4; ++nt) {
                accL[nt] = __builtin_amdgcn_mfma_f32_16x16x32_bf16(aSb, bMb[nt], accL[nt], 0, 0, 0);
                accD[nt] = __builtin_amdgcn_mfma_f32_16x16x32_bf16(aDb, bMb[nt], accD[nt], 0, 0, 0);
            }
            accH = __builtin_amdgcn_mfma_f32_16x16x32_bf16(aSb, bWb, accH, 0, 0, 0);
        }
    }

    // ---- classification head (all waves computed identical accH; wave 0 stores) ----
    if (w == 0 && la < 2) {
#pragma unroll
        for (int j = 0; j < 4; ++j) {
            int gr = row0 + lb * 4 + j;
            out[1 + gr * 2 + la] = accH[j] + bout[la];
        }
    }

    // ---- quarter-softmax: local max & sumexp over this wave's 64 cols ----
    ff4 mx = accL[0];
#pragma unroll
    for (int nt = 1; nt < 4; ++nt) {
        mx[0] = fmaxf(mx[0], accL[nt][0]); mx[1] = fmaxf(mx[1], accL[nt][1]);
        mx[2] = fmaxf(mx[2], accL[nt][2]); mx[3] = fmaxf(mx[3], accL[nt][3]);
    }
#pragma unroll
    for (int s = 1; s < 16; s <<= 1) {
        mx[0] = fmaxf(mx[0], __shfl_xor(mx[0], s));
        mx[1] = fmaxf(mx[1], __shfl_xor(mx[1], s));
        mx[2] = fmaxf(mx[2], __shfl_xor(mx[2], s));
        mx[3] = fmaxf(mx[3], __shfl_xor(mx[3], s));
    }
    ff4 sm = (ff4)0.0f;
#pragma unroll
    for (int nt = 0; nt < 4; ++nt) {
        sm[0] += __expf(accL[nt][0] - mx[0]); sm[1] += __expf(accL[nt][1] - mx[1]);
        sm[2] += __expf(accL[nt][2] - mx[2]); sm[3] += __expf(accL[nt][3] - mx[3]);
    }
#pragma unroll
    for (int s = 1; s < 16; s <<= 1) {
        sm[0] += __shfl_xor(sm[0], s); sm[1] += __shfl_xor(sm[1], s);
        sm[2] += __shfl_xor(sm[2], s); sm[3] += __shfl_xor(sm[3], s);
    }
    if (la < 4) {
        const int r = lb * 4 + la;
        float mv = (la == 0) ? mx[0] : (la == 1) ? mx[1] : (la == 2) ? mx[2] : mx[3];
        float sv = (la == 0) ? sm[0] : (la == 1) ? sm[1] : (la == 2) ? sm[2] : sm[3];
        fMax[w * 16 + r] = mv;
        fSum[w * 16 + r] = sv;
    }
    __syncthreads();   // all sS/sD reads done; fMax/fSum visible

    // ---- combine quarters -> per-row M, 1/denom ----
    ff4 Mr, Dinv;
#pragma unroll
    for (int j = 0; j < 4; ++j) {
        const int r = lb * 4 + j;
        float m0 = fMax[r], m1 = fMax[16 + r], m2 = fMax[32 + r], m3 = fMax[48 + r];
        float M = fmaxf(fmaxf(m0, m1), fmaxf(m2, m3));
        float den = fSum[r] * __expf(m0 - M) + fSum[16 + r] * __expf(m1 - M)
                  + fSum[32 + r] * __expf(m2 - M) + fSum[48 + r] * __expf(m3 - M);
        Mr[j] = M; Dinv[j] = 1.0f / den;
    }
    // ---- attn + cross partial ----
    ff4 cross = (ff4)0.0f;
#pragma unroll
    for (int nt = 0; nt < 4; ++nt) {
        accL[nt][0] = __expf(accL[nt][0] - Mr[0]) * Dinv[0];
        accL[nt][1] = __expf(accL[nt][1] - Mr[1]) * Dinv[1];
        accL[nt][2] = __expf(accL[nt][2] - Mr[2]) * Dinv[2];
        accL[nt][3] = __expf(accL[nt][3] - Mr[3]) * Dinv[3];
        cross[0] = fmaf(accL[nt][0], accD[nt][0], cross[0]);
        cross[1] = fmaf(accL[nt][1], accD[nt][1], cross[1]);
        cross[2] = fmaf(accL[nt][2], accD[nt][2], cross[2]);
        cross[3] = fmaf(accL[nt][3], accD[nt][3], cross[3]);
    }
#pragma unroll
    for (int s = 1; s < 16; s <<= 1) {
        cross[0] += __shfl_xor(cross[0], s); cross[1] += __shfl_xor(cross[1], s);
        cross[2] += __shfl_xor(cross[2], s); cross[3] += __shfl_xor(cross[3], s);
    }
    if (la < 4) {
        const int r = lb * 4 + la;
        float cv = (la == 0) ? cross[0] : (la == 1) ? cross[1] : (la == 2) ? cross[2] : cross[3];
        fCross[w * 16 + r] = cv;
    }
    // ---- stage attn rows (bf16) [16][264]; this wave's quarter (aliases sS) ----
    {
        const int rb = lb << 2;
#pragma unroll
        for (int nt = 0; nt < 4; ++nt) {
            const int cc = w * 64 + nt * 16 + la;
            sAttn[(rb + 0) * 264 + cc] = (unsigned short)bf16r(accL[nt][0]);
            sAttn[(rb + 1) * 264 + cc] = (unsigned short)bf16r(accL[nt][1]);
            sAttn[(rb + 2) * 264 + cc] = (unsigned short)bf16r(accL[nt][2]);
            sAttn[(rb + 3) * 264 + cc] = (unsigned short)bf16r(accL[nt][3]);
        }
    }
    __syncthreads();   // fCross + full attn visible

    // ---- gv = attn @ G over this wave's 64 output cols (G symmetric, Gcm contiguous) ----
    ff4 accG[4];
#pragma unroll
    for (int i = 0; i < 4; ++i) accG[i] = (ff4)0.0f;
#pragma unroll
    for (int ks = 0; ks < 8; ++ks) {
        s8v aA = *(const s8v*)(sAttn + la * 264 + ks * 32 + lb * 8);
        const unsigned short* gp = gbase + (size_t)ks * 8192;
#pragma unroll
        for (int nt = 0; nt < 4; ++nt) {
            s8v bG = *(const s8v*)(gp + nt * 512);
            accG[nt] = __builtin_amdgcn_mfma_f32_16x16x32_bf16(aA, bG, accG[nt], 0, 0, 0);
        }
    }
    ff4 quad = (ff4)0.0f;
#pragma unroll
    for (int nt = 0; nt < 4; ++nt) {
        quad[0] = fmaf(accL[nt][0], accG[nt][0], quad[0]);
        quad[1] = fmaf(accL[nt][1], accG[nt][1], quad[1]);
        quad[2] = fmaf(accL[nt][2], accG[nt][2], quad[2]);
        quad[3] = fmaf(accL[nt][3], accG[nt][3], quad[3]);
    }
#pragma unroll
    for (int s = 1; s < 16; s <<= 1) {
        quad[0] += __shfl_xor(quad[0], s); quad[1] += __shfl_xor(quad[1], s);
        quad[2] += __shfl_xor(quad[2], s); quad[3] += __shfl_xor(quad[3], s);
    }
    if (la < 4) {
        const int r = lb * 4 + la;
        float qv = (la == 0) ? quad[0] : (la == 1) ? quad[1] : (la == 2) ? quad[2] : quad[3];
        fQuad[w * 16 + r] = qv;
    }
    __syncthreads();

    // ---- score & per-block loss partial (wave 0) ----
    float val = 0.f;
    if (w == 0 && l < 16) {
        float aux = fAux[l] + fAux[16 + l] + fAux[32 + l] + fAux[48 + l];
        float cr  = fCross[l] + fCross[16 + l] + fCross[32 + l] + fCross[48 + l];
        float qd  = fQuad[l] + fQuad[16 + l] + fQuad[32 + l] + fQuad[48 + l];
        float s2 = aux + 2.0f * cr + qd;
        float sc = sqrtf(fmaxf(s2, 0.0f));
        val = (float)(2 * label[row0 + l] - 1) * sc;
    }
#pragma unroll
    for (int s = 1; s < 64; s <<= 1) val += __shfl_xor(val, s);
    if (t == 0) partials[blockIdx.x] = val;
}

// ---- deterministic final reduction of per-block partials -> loss ----
__global__ void finalize_kernel(const float* __restrict__ partials, float* __restrict__ out,
                                int np, float invB) {
    const int t = threadIdx.x;
    float v = 0.f;
    for (int i = t; i < np; i += 256) v += partials[i];
#pragma unroll
    for (int s = 1; s < 64; s <<= 1) v += __shfl_xor(v, s);
    __shared__ float ws4[4];
    if ((t & 63) == 0) ws4[t >> 6] = v;
    __syncthreads();
    if (t == 0) out[0] = (ws4[0] + ws4[1] + ws4[2] + ws4[3]) * invB;
}

extern "C" void kernel_launch(void* const* d_in, const int* in_sizes, int n_in,
                              void* d_out, int out_size, void* d_ws, size_t ws_size,
                              hipStream_t stream) {
    const float* user  = (const float*)d_in[0];
    const float* music = (const float*)d_in[1];
    const float* mem   = (const float*)d_in[2];
    const float* Wout  = (const float*)d_in[3];
    const float* bout  = (const float*)d_in[4];
    const int*   label = (const int*)d_in[5];
    const int Bn   = in_sizes[0] / Hd;   // 65536
    const int nblk = Bn / RB;            // 4096

    unsigned short* memB = (unsigned short*)d_ws;                                  // 512 KB
    unsigned short* Wbf  = (unsigned short*)((char*)d_ws + 524288);                // 4 KB
    unsigned short* Gcm  = (unsigned short*)((char*)d_ws + 524288 + 4096);         // 128 KB
    float* partials      = (float*)((char*)d_ws + 524288 + 4096 + 131072);         // 16 KB

    conv_mem_kernel<<<128, 256, 0, stream>>>(mem, memB);
    conv_w_kernel<<<1, 256, 0, stream>>>(Wout, Wbf);
    gram_kernel<<<64, 256, 0, stream>>>(mem, Gcm);
    fused_kernel<<<nblk, 256, 0, stream>>>(user, music, bout, label, memB, Wbf, Gcm,
                                           (float*)d_out, partials);
    finalize_kernel<<<1, 256, 0, stream>>>(partials, (float*)d_out, nblk, 1.0f / (float)Bn);
}

// Round 11
// 269.347 us; speedup vs baseline: 1.2343x; 1.2343x over previous
//
#include <hip/hip_runtime.h>
#include <hip/hip_bf16.h>

typedef float ff4 __attribute__((ext_vector_type(4)));
typedef short s8v __attribute__((ext_vector_type(8)));
typedef unsigned int u4v __attribute__((ext_vector_type(4)));
typedef unsigned int u2v __attribute__((ext_vector_type(2)));

#define Hd 1024
#define Nn 256
#define RB 16
#define HSTR 520    // sS/sD row stride in ushorts (512 + 8 pad)

__device__ __forceinline__ unsigned bf16r(float f) {
    unsigned u = __builtin_bit_cast(unsigned, f);
    return (u + 0x7FFFu + ((u >> 16) & 1u)) >> 16;   // RNE f32->bf16
}

__device__ __forceinline__ unsigned cvtpk(float lo, float hi) {
    unsigned r;
    asm("v_cvt_pk_bf16_f32 %0, %1, %2" : "=v"(r) : "v"(lo), "v"(hi));
    return r;
}

// ---- memB chunk-major LINEAR: memB[c*8192 + r*32 + col] = bf16(mem[r][c*32+col]) ----
__global__ void conv_mem_kernel(const float* __restrict__ mem, unsigned short* __restrict__ memB) {
    int g = blockIdx.x * 256 + threadIdx.x;   // 0..32767
    int b = g & 3;
    int r = (g >> 2) & 255;
    int c = g >> 10;
    const float* src = mem + (size_t)r * Hd + c * 32 + b * 8;
    ff4 a0 = *(const ff4*)src;
    ff4 a1 = *(const ff4*)(src + 4);
    u4v v;
    v[0] = bf16r(a0[0]) | (bf16r(a0[1]) << 16);
    v[1] = bf16r(a0[2]) | (bf16r(a0[3]) << 16);
    v[2] = bf16r(a1[0]) | (bf16r(a1[1]) << 16);
    v[3] = bf16r(a1[2]) | (bf16r(a1[3]) << 16);
    *(u4v*)(memB + (size_t)c * 8192 + (size_t)r * 32 + b * 8) = v;
}

// ---- Wbf[c][h] = bf16(Wout[h][c]), c in {0,1} ----
__global__ void conv_w_kernel(const float* __restrict__ Wout, unsigned short* __restrict__ Wbf) {
    int t = threadIdx.x;
    int c = t >> 7;
    int h0 = (t & 127) * 8;
    u4v v;
#pragma unroll
    for (int j = 0; j < 4; ++j) {
        unsigned lo = bf16r(Wout[(h0 + 2 * j) * 2 + c]);
        unsigned hi = bf16r(Wout[(h0 + 2 * j + 1) * 2 + c]);
        v[j] = lo | (hi << 16);
    }
    *(u4v*)(Wbf + (size_t)c * Hd + h0) = v;
}

// ---- Gram G = mem @ mem^T, chunk-major: Gcm[(gj>>5)*8192 + gi*32 + (gj&31)] ----
__global__ __launch_bounds__(256) void gram_kernel(const float* __restrict__ mem,
                                                   unsigned short* __restrict__ Gcm) {
    __shared__ float LA[32][132];
    __shared__ float LB[32][132];
    const int t = threadIdx.x;
    const int bi = blockIdx.x >> 3, bj = blockIdx.x & 7;
    const int j = t & 31, i0 = t >> 5;
    float acc0 = 0.f, acc1 = 0.f, acc2 = 0.f, acc3 = 0.f;
    for (int kc = 0; kc < Hd; kc += 128) {
        __syncthreads();
#pragma unroll
        for (int q = 0; q < 4; ++q) {
            int c = t + q * 256;
            int r = c >> 5, fc = (c & 31) << 2;
            *(ff4*)&LA[r][fc] = *(const ff4*)(mem + (size_t)(bi * 32 + r) * Hd + kc + fc);
            *(ff4*)&LB[r][fc] = *(const ff4*)(mem + (size_t)(bj * 32 + r) * Hd + kc + fc);
        }
        __syncthreads();
#pragma unroll 4
        for (int kk = 0; kk < 128; kk += 4) {
            ff4 b = *(const ff4*)&LB[j][kk];
            ff4 a0 = *(const ff4*)&LA[i0][kk];
            ff4 a1 = *(const ff4*)&LA[i0 + 8][kk];
            ff4 a2 = *(const ff4*)&LA[i0 + 16][kk];
            ff4 a3 = *(const ff4*)&LA[i0 + 24][kk];
            acc0 += a0[0]*b[0] + a0[1]*b[1] + a0[2]*b[2] + a0[3]*b[3];
            acc1 += a1[0]*b[0] + a1[1]*b[1] + a1[2]*b[2] + a1[3]*b[3];
            acc2 += a2[0]*b[0] + a2[1]*b[1] + a2[2]*b[2] + a2[3]*b[3];
            acc3 += a3[0]*b[0] + a3[1]*b[1] + a3[2]*b[2] + a3[3]*b[3];
        }
    }
    const size_t base = (size_t)bj * 8192 + (size_t)j;
    Gcm[base + (size_t)(bi * 32 + i0 +  0) * 32] = (unsigned short)bf16r(acc0);
    Gcm[base + (size_t)(bi * 32 + i0 +  8) * 32] = (unsigned short)bf16r(acc1);
    Gcm[base + (size_t)(bi * 32 + i0 + 16) * 32] = (unsigned short)bf16r(acc2);
    Gcm[base + (size_t)(bi * 32 + i0 + 24) * 32] = (unsigned short)bf16r(acc3);
}

// ---- fused: 16 rows/block; 2 x {stream half-K -> LDS, GEMM half-K};
//      small LDS (34 KB) -> 3 blocks/CU; 4 waves = 4 column-quarters of N=256 ----
__global__ __launch_bounds__(256, 3) void fused_kernel(
    const float* __restrict__ user, const float* __restrict__ music,
    const float* __restrict__ bout, const int* __restrict__ label,
    const unsigned short* __restrict__ memB,   // [32][256][32] bf16 chunk-major
    const unsigned short* __restrict__ Wbf,    // [2][1024] bf16
    const unsigned short* __restrict__ Gcm,    // [8][256][32] bf16 chunk-major
    float* __restrict__ out, float* __restrict__ partials)
{
    __shared__ __align__(16) unsigned short sS[RB * HSTR];   // 16640 B
    __shared__ __align__(16) unsigned short sD[RB * HSTR];   // 16640 B
    __shared__ float fMax[64], fSum[64], fCross[64], fQuad[64], fAux[16];
    unsigned short* sAttn = sS;   // epilogue alias [16][264]

    const int t = threadIdx.x;
    const int w = t >> 6;
    const int l = t & 63;
    const int la = l & 15, lb = l >> 4;
    const int row0 = blockIdx.x * RB;

    // streaming role: thread = (row srow, col-group scol)
    const int srow = t >> 4;
    const int scol = t & 15;
    const float* uRow = user  + (size_t)(row0 + srow) * Hd + scol * 4;
    const float* mRow = music + (size_t)(row0 + srow) * Hd + scol * 4;

    // GEMM role
    const unsigned short* mbase = memB + w * 2048 + la * 32 + lb * 8;   // + c*8192 + nt*512
    const unsigned short* wrowB = Wbf + (size_t)(la < 2 ? la : 1) * Hd + lb * 8;
    const unsigned short* gbase = Gcm + w * 2048 + la * 32 + lb * 8;
    const int aoff = la * HSTR + lb * 8;

    ff4 accL[4], accD[4];
#pragma unroll
    for (int i = 0; i < 4; ++i) { accL[i] = (ff4)0.0f; accD[i] = (ff4)0.0f; }
    ff4 accH = (ff4)0.0f;
    float sd2 = 0.f;

#pragma unroll
    for (int hh = 0; hh < 2; ++hh) {
        // ---- stream half hh: u/m -> s,d bf16 in LDS ----
#pragma unroll
        for (int i = 0; i < 8; ++i) {
            const int off = hh * 512 + 64 * i;
            ff4 uv = *(const ff4*)(uRow + off);
            ff4 mv = *(const ff4*)(mRow + off);
            float s0 = uv[0]*mv[0], s1 = uv[1]*mv[1], s2 = uv[2]*mv[2], s3 = uv[3]*mv[3];
            float d0 = uv[0]-mv[0], d1 = uv[1]-mv[1], d2 = uv[2]-mv[2], d3 = uv[3]-mv[3];
            sd2 = fmaf(d0,d0,sd2); sd2 = fmaf(d1,d1,sd2);
            sd2 = fmaf(d2,d2,sd2); sd2 = fmaf(d3,d3,sd2);
            u2v vs, vd;
            vs[0] = cvtpk(s0, s1); vs[1] = cvtpk(s2, s3);
            vd[0] = cvtpk(d0, d1); vd[1] = cvtpk(d2, d3);
            *(u2v*)(sS + srow * HSTR + scol * 4 + 64 * i) = vs;
            *(u2v*)(sD + srow * HSTR + scol * 4 + 64 * i) = vd;
        }
        __syncthreads();   // half tile ready

        // ---- GEMM half hh (16 chunks of KC=32), depth-1 parity prefetch ----
        {
            const int c0 = hh * 16;
            s8v bMa[4], bMb[4], bWa, bWb, aSa, aSb, aDa, aDb;
#pragma unroll
            for (int nt = 0; nt < 4; ++nt)
                bMa[nt] = *(const s8v*)(mbase + (size_t)c0 * 8192 + nt * 512);
            bWa = *(const s8v*)(wrowB + c0 * 32);
            aSa = *(const s8v*)(sS + aoff);
            aDa = *(const s8v*)(sD + aoff);
#pragma unroll
            for (int kk = 0; kk < 16; kk += 2) {
                const int k1 = (kk + 1) & 15;
#pragma unroll
                for (int nt = 0; nt < 4; ++nt)
                    bMb[nt] = *(const s8v*)(mbase + (size_t)(c0 + k1) * 8192 + nt * 512);
                bWb = *(const s8v*)(wrowB + (c0 + k1) * 32);
                aSb = *(const s8v*)(sS + aoff + k1 * 32);
                aDb = *(const s8v*)(sD + aoff + k1 * 32);
#pragma unroll
                for (int nt = 0; nt < 4; ++nt) {
                    accL[nt] = __builtin_amdgcn_mfma_f32_16x16x32_bf16(aSa, bMa[nt], accL[nt], 0, 0, 0);
                    accD[nt] = __builtin_amdgcn_mfma_f32_16x16x32_bf16(aDa, bMa[nt], accD[nt], 0, 0, 0);
                }
                accH = __builtin_amdgcn_mfma_f32_16x16x32_bf16(aSa, bWa, accH, 0, 0, 0);
                const int k2 = (kk + 2) & 15;
#pragma unroll
                for (int nt = 0; nt < 4; ++nt)
                    bMa[nt] = *(const s8v*)(mbase + (size_t)(c0 + k2) * 8192 + nt * 512);
                bWa = *(const s8v*)(wrowB + (c0 + k2) * 32);
                aSa = *(const s8v*)(sS + aoff + k2 * 32);
                aDa = *(const s8v*)(sD + aoff + k2 * 32);
#pragma unroll
                for (int nt = 0; nt < 4; ++nt) {
                    accL[nt] = __builtin_amdgcn_mfma_f32_16x16x32_bf16(aSb, bMb[nt], accL[nt], 0, 0, 0);
                    accD[nt] = __builtin_amdgcn_mfma_f32_16x16x32_bf16(aDb, bMb[nt], accD[nt], 0, 0, 0);
                }
                accH = __builtin_amdgcn_mfma_f32_16x16x32_bf16(aSb, bWb, accH, 0, 0, 0);
            }
        }
        __syncthreads();   // all sS/sD reads done; safe to overwrite next half / epilogue
    }

    // ---- classification head (cols 0,1 live in lanes la<2; wave 0 stores) ----
    if (w == 0 && la < 2) {
#pragma unroll
        for (int j = 0; j < 4; ++j) {
            int gr = row0 + lb * 4 + j;
            out[1 + gr * 2 + la] = accH[j] + bout[la];
        }
    }

    // ---- ||d||^2 per row: reduce over 16 col-group threads of each row ----
    sd2 += __shfl_xor(sd2, 1);
    sd2 += __shfl_xor(sd2, 2);
    sd2 += __shfl_xor(sd2, 4);
    sd2 += __shfl_xor(sd2, 8);
    if ((l & 15) == 0) fAux[w * 4 + (l >> 4)] = sd2;   // row srow = w*4 + (l>>4)

    // ---- quarter-softmax: local max & sumexp over this wave's 64 cols ----
    ff4 mx = accL[0];
#pragma unroll
    for (int nt = 1; nt < 4; ++nt) {
        mx[0] = fmaxf(mx[0], accL[nt][0]); mx[1] = fmaxf(mx[1], accL[nt][1]);
        mx[2] = fmaxf(mx[2], accL[nt][2]); mx[3] = fmaxf(mx[3], accL[nt][3]);
    }
#pragma unroll
    for (int s = 1; s < 16; s <<= 1) {
        mx[0] = fmaxf(mx[0], __shfl_xor(mx[0], s));
        mx[1] = fmaxf(mx[1], __shfl_xor(mx[1], s));
        mx[2] = fmaxf(mx[2], __shfl_xor(mx[2], s));
        mx[3] = fmaxf(mx[3], __shfl_xor(mx[3], s));
    }
    ff4 sm = (ff4)0.0f;
#pragma unroll
    for (int nt = 0; nt < 4; ++nt) {
        sm[0] += __expf(accL[nt][0] - mx[0]); sm[1] += __expf(accL[nt][1] - mx[1]);
        sm[2] += __expf(accL[nt][2] - mx[2]); sm[3] += __expf(accL[nt][3] - mx[3]);
    }
#pragma unroll
    for (int s = 1; s < 16; s <<= 1) {
        sm[0] += __shfl_xor(sm[0], s); sm[1] += __shfl_xor(sm[1], s);
        sm[2] += __shfl_xor(sm[2], s); sm[3] += __shfl_xor(sm[3], s);
    }
    if (la < 4) {
        const int r = lb * 4 + la;
        float mv = (la == 0) ? mx[0] : (la == 1) ? mx[1] : (la == 2) ? mx[2] : mx[3];
        float sv = (la == 0) ? sm[0] : (la == 1) ? sm[1] : (la == 2) ? sm[2] : sm[3];
        fMax[w * 16 + r] = mv;
        fSum[w * 16 + r] = sv;
    }
    __syncthreads();

    // ---- combine quarters -> per-row M, 1/denom ----
    ff4 Mr, Dinv;
#pragma unroll
    for (int j = 0; j < 4; ++j) {
        const int r = lb * 4 + j;
        float m0 = fMax[r], m1 = fMax[16 + r], m2 = fMax[32 + r], m3 = fMax[48 + r];
        float M = fmaxf(fmaxf(m0, m1), fmaxf(m2, m3));
        float den = fSum[r] * __expf(m0 - M) + fSum[16 + r] * __expf(m1 - M)
                  + fSum[32 + r] * __expf(m2 - M) + fSum[48 + r] * __expf(m3 - M);
        Mr[j] = M; Dinv[j] = 1.0f / den;
    }
    // ---- attn + cross partial ----
    ff4 cross = (ff4)0.0f;
#pragma unroll
    for (int nt = 0; nt < 4; ++nt) {
        accL[nt][0] = __expf(accL[nt][0] - Mr[0]) * Dinv[0];
        accL[nt][1] = __expf(accL[nt][1] - Mr[1]) * Dinv[1];
        accL[nt][2] = __expf(accL[nt][2] - Mr[2]) * Dinv[2];
        accL[nt][3] = __expf(accL[nt][3] - Mr[3]) * Dinv[3];
        cross[0] = fmaf(accL[nt][0], accD[nt][0], cross[0]);
        cross[1] = fmaf(accL[nt][1], accD[nt][1], cross[1]);
        cross[2] = fmaf(accL[nt][2], accD[nt][2], cross[2]);
        cross[3] = fmaf(accL[nt][3], accD[nt][3], cross[3]);
    }
#pragma unroll
    for (int s = 1; s < 16; s <<= 1) {
        cross[0] += __shfl_xor(cross[0], s); cross[1] += __shfl_xor(cross[1], s);
        cross[2] += __shfl_xor(cross[2], s); cross[3] += __shfl_xor(cross[3], s);
    }
    if (la < 4) {
        const int r = lb * 4 + la;
        float cv = (la == 0) ? cross[0] : (la == 1) ? cross[1] : (la == 2) ? cross[2] : cross[3];
        fCross[w * 16 + r] = cv;
    }
    // ---- stage attn rows (bf16) [16][264]; this wave's quarter (aliases sS) ----
    {
        const int rb = lb << 2;
#pragma unroll
        for (int nt = 0; nt < 4; ++nt) {
            const int cc = w * 64 + nt * 16 + la;
            sAttn[(rb + 0) * 264 + cc] = (unsigned short)bf16r(accL[nt][0]);
            sAttn[(rb + 1) * 264 + cc] = (unsigned short)bf16r(accL[nt][1]);
            sAttn[(rb + 2) * 264 + cc] = (unsigned short)bf16r(accL[nt][2]);
            sAttn[(rb + 3) * 264 + cc] = (unsigned short)bf16r(accL[nt][3]);
        }
    }
    __syncthreads();

    // ---- gv = attn @ G over this wave's 64 output cols (G symmetric, Gcm contiguous) ----
    ff4 accG[4];
#pragma unroll
    for (int i = 0; i < 4; ++i) accG[i] = (ff4)0.0f;
#pragma unroll
    for (int ks = 0; ks < 8; ++ks) {
        s8v aA = *(const s8v*)(sAttn + la * 264 + ks * 32 + lb * 8);
        const unsigned short* gp = gbase + (size_t)ks * 8192;
#pragma unroll
        for (int nt = 0; nt < 4; ++nt) {
            s8v bG = *(const s8v*)(gp + nt * 512);
            accG[nt] = __builtin_amdgcn_mfma_f32_16x16x32_bf16(aA, bG, accG[nt], 0, 0, 0);
        }
    }
    ff4 quad = (ff4)0.0f;
#pragma unroll
    for (int nt = 0; nt < 4; ++nt) {
        quad[0] = fmaf(accL[nt][0], accG[nt][0], quad[0]);
        quad[1] = fmaf(accL[nt][1], accG[nt][1], quad[1]);
        quad[2] = fmaf(accL[nt][2], accG[nt][2], quad[2]);
        quad[3] = fmaf(accL[nt][3], accG[nt][3], quad[3]);
    }
#pragma unroll
    for (int s = 1; s < 16; s <<= 1) {
        quad[0] += __shfl_xor(quad[0], s); quad[1] += __shfl_xor(quad[1], s);
        quad[2] += __shfl_xor(quad[2], s); quad[3] += __shfl_xor(quad[3], s);
    }
    if (la < 4) {
        const int r = lb * 4 + la;
        float qv = (la == 0) ? quad[0] : (la == 1) ? quad[1] : (la == 2) ? quad[2] : quad[3];
        fQuad[w * 16 + r] = qv;
    }
    __syncthreads();

    // ---- score & per-block loss partial (wave 0) ----
    float val = 0.f;
    if (w == 0 && l < 16) {
        float cr  = fCross[l] + fCross[16 + l] + fCross[32 + l] + fCross[48 + l];
        float qd  = fQuad[l] + fQuad[16 + l] + fQuad[32 + l] + fQuad[48 + l];
        float s2 = fAux[l] + 2.0f * cr + qd;
        float sc = sqrtf(fmaxf(s2, 0.0f));
        val = (float)(2 * label[row0 + l] - 1) * sc;
    }
#pragma unroll
    for (int s = 1; s < 64; s <<= 1) val += __shfl_xor(val, s);
    if (t == 0) partials[blockIdx.x] = val;
}

// ---- deterministic final reduction of per-block partials -> loss ----
__global__ void finalize_kernel(const float* __restrict__ partials, float* __restrict__ out,
                                int np, float invB) {
    const int t = threadIdx.x;
    float v = 0.f;
    for (int i = t; i < np; i += 256) v += partials[i];
#pragma unroll
    for (int s = 1; s < 64; s <<= 1) v += __shfl_xor(v, s);
    __shared__ float ws4[4];
    if ((t & 63) == 0) ws4[t >> 6] = v;
    __syncthreads();
    if (t == 0) out[0] = (ws4[0] + ws4[1] + ws4[2] + ws4[3]) * invB;
}

extern "C" void kernel_launch(void* const* d_in, const int* in_sizes, int n_in,
                              void* d_out, int out_size, void* d_ws, size_t ws_size,
                              hipStream_t stream) {
    const float* user  = (const float*)d_in[0];
    const float* music = (const float*)d_in[1];
    const float* mem   = (const float*)d_in[2];
    const float* Wout  = (const float*)d_in[3];
    const float* bout  = (const float*)d_in[4];
    const int*   label = (const int*)d_in[5];
    const int Bn   = in_sizes[0] / Hd;   // 65536
    const int nblk = Bn / RB;            // 4096

    unsigned short* memB = (unsigned short*)d_ws;                                  // 512 KB
    unsigned short* Wbf  = (unsigned short*)((char*)d_ws + 524288);                // 4 KB
    unsigned short* Gcm  = (unsigned short*)((char*)d_ws + 524288 + 4096);         // 128 KB
    float* partials      = (float*)((char*)d_ws + 524288 + 4096 + 131072);         // 16 KB

    conv_mem_kernel<<<128, 256, 0, stream>>>(mem, memB);
    conv_w_kernel<<<1, 256, 0, stream>>>(Wout, Wbf);
    gram_kernel<<<64, 256, 0, stream>>>(mem, Gcm);
    fused_kernel<<<nblk, 256, 0, stream>>>(user, music, bout, label, memB, Wbf, Gcm,
                                           (float*)d_out, partials);
    finalize_kernel<<<1, 256, 0, stream>>>(partials, (float*)d_out, nblk, 1.0f / (float)Bn);
}